// Round 13
// baseline (235.620 us; speedup 1.0000x reference)
//
#include <hip/hip_runtime.h>
#include <cstddef>

#define N_NODES 10000
#define N_EDGES 160000
#define E_TOT   170000
#define N_GRAPHS 64
#define NF 64
#define HID 128
#define HC 512
#define LAT 64
#define MAXN 50
#define NPAIR 1225
#define NODESF 3200
#define DEG_CAP 64

typedef __attribute__((ext_vector_type(8))) short bf16x8;
typedef __attribute__((ext_vector_type(8))) unsigned short u16x8;
typedef __attribute__((ext_vector_type(4))) float f32x4;
typedef unsigned short u16;
typedef unsigned int u32;

__device__ __forceinline__ u16 f2b(float f) {
    u32 u = __float_as_uint(f);
    u32 r = (u + 0x7fffu + ((u >> 16) & 1u)) >> 16;
    return (u16)r;
}
__device__ __forceinline__ float b2f(u16 v) {
    return __uint_as_float(((u32)v) << 16);
}

// ====== pack_all: weights -> bf16 B-frag, x -> bf16, pairs, bucket CSR, w_esed precompute ======
struct PackArgs {
    const float* src[15];
    u16* dst[15];
};
#define PACK_TOTAL 344192
#define PACK_W 3072   // w_esed: 3 layers x {es,ed} x 4 heads x 128 dims
#define PACK_GRID_TOTAL (PACK_TOTAL + NPAIR + E_TOT + PACK_W)
__global__ void pack_all_kernel(PackArgs pa, int* __restrict__ pi, int* __restrict__ pj,
                                const int* __restrict__ ei, int* __restrict__ cursor,
                                int* __restrict__ csr_src,
                                const float* __restrict__ Wg, const float* __restrict__ ags,
                                const float* __restrict__ agd, float* __restrict__ wesed) {
    int idx = blockIdx.x * 256 + threadIdx.x;
    if (idx >= PACK_GRID_TOTAL) return;
    if (idx >= PACK_TOTAL) {
        int r = idx - PACK_TOTAL;
        if (r < NPAIR) {
            int i = 0, off = 0;
            while (off + (MAXN - 1 - i) <= r) { off += MAXN - 1 - i; ++i; }
            pi[r] = i;
            pj[r] = i + 1 + (r - off);
        } else if (r < NPAIR + E_TOT) {
            // bucket CSR fill: order within bucket irrelevant
            int e = r - NPAIR;
            int s, d;
            if (e < N_EDGES) { s = ei[e]; d = ei[N_EDGES + e]; }
            else { s = e - N_EDGES; d = s; }
            int pos = atomicAdd(&cursor[d], 1);
            csr_src[(d << 6) + pos] = s;   // DEG_CAP=64; max real degree ~40 (verified R9/R10)
        } else {
            // w_esed[l][sd][h][k] = sum_c Wg[l][k][h*128+c] * ag[l][h][c]
            int i = r - NPAIR - E_TOT;     // < 3072
            int l = i >> 10, rr = i & 1023;
            int sd = rr >> 9, hh = (rr >> 7) & 3, k = rr & 127;
            const float* wrow = Wg + ((size_t)(l * 128 + k)) * 512 + hh * 128;
            const float* ag = (sd ? agd : ags) + (l * 4 + hh) * 128;
            float s = 0.f;
#pragma unroll 8
            for (int c = 0; c < 128; ++c) s = fmaf(wrow[c], ag[c], s);
            wesed[(l * 8 + sd * 4 + hh) * 128 + k] = s;
        }
        return;
    }
    const int base[16] = {0, 8192, 16384, 24576, 27648, 28672, 29696, 33792, 37888,
                          38912, 39936, 41984, 58368, 263168, 264192, 344192};
    const int Ns[15]   = {512, 512, 512, 128, 64, 64, 256, 128, 64, 64, 256, 512, 3200, 128, 0};
    const int dNs[15]  = {512, 512, 512, 128, 64, 64, 256, 128, 128, 128, 256, 512, 3200, 128, 0};
    const int coff[15] = {0, 0, 0, 0, 0, 0, 0, 0, 0, 64, 0, 0, 0, 0, 0};
    int s = 0;
    while (idx >= base[s + 1]) ++s;
    int i = idx - base[s];
    const float* sp = pa.src[s];
    u16* dp = pa.dst[s];
    if (s == 14) {
        u16x8 o;
#pragma unroll
        for (int j = 0; j < 8; ++j) o[j] = f2b(sp[(size_t)i * 8 + j]);
        *(u16x8*)&dp[(size_t)i * 8] = o;
        return;
    }
    int N = Ns[s];
    int g = i / N, n = i - g * N;
    u16x8 o;
#pragma unroll
    for (int j = 0; j < 8; ++j) o[j] = f2b(sp[(size_t)(g * 8 + j) * N + n]);
    *(u16x8*)&dp[((size_t)g * dNs[s] + n + coff[s]) * 8] = o;
}

// ================= gemm_mh: M-large MFMA GEMM, 64 rows x CB cols per block =================
template<int K, int NT, int CB, bool BIAS, bool RELU, bool F32OUT>
__global__ __launch_bounds__(256) void gemm_mh_kernel(const u16* __restrict__ A,
                                                      const u16* __restrict__ Wp,
                                                      const float* __restrict__ bias,
                                                      u16* __restrict__ bo,
                                                      float* __restrict__ fo) {
    constexpr int CT = CB / 64;
    __shared__ u16 AL[64 * (K + 8)];
    int t = threadIdx.x, w = t >> 6, l = t & 63, lr = l & 15, lg = l >> 4;
    int rb = blockIdx.x * 64, j0 = blockIdx.y * CB;
    for (int u = t; u < 64 * (K / 8); u += 256) {
        int r = u / (K / 8), c8 = (u % (K / 8)) * 8;
        int row = min(rb + r, N_NODES - 1);
        *(u16x8*)&AL[r * (K + 8) + c8] = *(const u16x8*)&A[(size_t)row * K + c8];
    }
    __syncthreads();
    f32x4 acc[4][CT];
#pragma unroll
    for (int rt = 0; rt < 4; ++rt)
#pragma unroll
        for (int ct = 0; ct < CT; ++ct) acc[rt][ct] = (f32x4){0.f, 0.f, 0.f, 0.f};
#pragma unroll
    for (int ks = 0; ks < K / 32; ++ks) {
        bf16x8 a[4], b[CT];
#pragma unroll
        for (int rt = 0; rt < 4; ++rt)
            a[rt] = *(const bf16x8*)&AL[(rt * 16 + lr) * (K + 8) + ks * 32 + lg * 8];
#pragma unroll
        for (int ct = 0; ct < CT; ++ct) {
            int col = j0 + w * (CB / 4) + ct * 16 + lr;
            b[ct] = *(const bf16x8*)&Wp[(size_t)((ks * 4 + lg) * NT + col) * 8];
        }
#pragma unroll
        for (int rt = 0; rt < 4; ++rt)
#pragma unroll
            for (int ct = 0; ct < CT; ++ct)
                acc[rt][ct] = __builtin_amdgcn_mfma_f32_16x16x32_bf16(a[rt], b[ct], acc[rt][ct], 0, 0, 0);
    }
#pragma unroll
    for (int rt = 0; rt < 4; ++rt)
#pragma unroll
        for (int ct = 0; ct < CT; ++ct) {
            int col = j0 + w * (CB / 4) + ct * 16 + lr;
            float bj = BIAS ? bias[col] : 0.f;
#pragma unroll
            for (int i = 0; i < 4; ++i) {
                int row = rb + rt * 16 + lg * 4 + i;
                if (row < N_NODES) {
                    float v = acc[rt][ct][i] + bj;
                    if (RELU) v = fmaxf(v, 0.f);
                    bo[(size_t)row * NT + col] = f2b(v);
                    if (F32OUT) fo[(size_t)row * NT + col] = v;
                }
            }
        }
}

// ================= gemm64: M=64 skinny MFMA GEMM with intra-block split-K =================
template<int K, int G, int ACT, bool SPLIT>
__global__ __launch_bounds__(256) void gemm64_kernel(const u16* __restrict__ A,
                                                     const u16* __restrict__ Wp,
                                                     const float* __restrict__ bias,
                                                     const float* __restrict__ bias2,
                                                     float* __restrict__ fo,
                                                     float* __restrict__ fo2,
                                                     u16* __restrict__ bo, int N) {
    constexpr int CG = 4 / G, NB = CG * 16, Kc = K / G, KS = Kc / 32;
    constexpr int ABYTES = 64 * (K + 8) * 2;
    constexpr int LDSB = (ABYTES > 16384) ? ABYTES : 16384;
    __shared__ float LDSf[LDSB / 4];
    u16* AL = (u16*)LDSf;
    float* RB = LDSf;
    int t = threadIdx.x, w = t >> 6, l = t & 63, lr = l & 15, lg = l >> 4;
    for (int u = t; u < 64 * (K / 8); u += 256) {
        int r = u / (K / 8), c8 = (u % (K / 8)) * 8;
        *(u16x8*)&AL[r * (K + 8) + c8] = *(const u16x8*)&A[(size_t)r * K + c8];
    }
    __syncthreads();
    int kg = w % G, cg = w / G;
    int col = blockIdx.x * NB + cg * 16 + lr;
    f32x4 acc[4];
#pragma unroll
    for (int rt = 0; rt < 4; ++rt) acc[rt] = (f32x4){0.f, 0.f, 0.f, 0.f};
#pragma unroll
    for (int ks = 0; ks < KS; ++ks) {
        int k0 = kg * Kc + ks * 32;
        bf16x8 b = *(const bf16x8*)&Wp[(size_t)(((k0 >> 3) + lg) * N + col) * 8];
#pragma unroll
        for (int rt = 0; rt < 4; ++rt) {
            bf16x8 a = *(const bf16x8*)&AL[(rt * 16 + lr) * (K + 8) + k0 + lg * 8];
            acc[rt] = __builtin_amdgcn_mfma_f32_16x16x32_bf16(a, b, acc[rt], 0, 0, 0);
        }
    }
    __syncthreads();
#pragma unroll
    for (int rt = 0; rt < 4; ++rt)
#pragma unroll
        for (int i = 0; i < 4; ++i)
            RB[w * 1024 + (rt * 16 + lg * 4 + i) * 16 + lr] = acc[rt][i];
    __syncthreads();
    for (int e = t; e < 64 * NB; e += 256) {
        int row = e / NB, cb = e - row * NB;
        int cg2 = cb >> 4, cl = cb & 15;
        float s = 0.f;
#pragma unroll
        for (int kg2 = 0; kg2 < G; ++kg2)
            s += RB[(cg2 * G + kg2) * 1024 + row * 16 + cl];
        int c = blockIdx.x * NB + cb;
        float bj;
        if (SPLIT) bj = (c < 64) ? bias[c] : bias2[c - 64];
        else bj = bias[c];
        float v = s + bj;
        if (ACT == 1) v = fmaxf(v, 0.f);
        if (bo) bo[(size_t)row * N + c] = f2b(v);
        if (SPLIT) {
            if (c < 64) fo[row * 64 + c] = v;
            else fo2[row * 64 + (c - 64)] = v;
        } else if (fo) {
            float ov = (ACT == 2) ? 1.f / (1.f + __expf(-v)) : v;
            fo[(size_t)row * N + c] = ov;
        }
    }
}

// ================= mm64: in-kernel M=64 MFMA sub-GEMM =================
template<int K, int N, typename EP>
__device__ __forceinline__ void mm64(const u16* __restrict__ AL, int lda,
                                     const u16* __restrict__ Wp, EP ep) {
    int t = threadIdx.x, w = t >> 6, l = t & 63, lr = l & 15, lg = l >> 4;
#pragma unroll
    for (int p = 0; p < N / 64; ++p) {
        int col = p * 64 + w * 16 + lr;
        f32x4 acc[4];
#pragma unroll
        for (int rt = 0; rt < 4; ++rt) acc[rt] = (f32x4){0.f, 0.f, 0.f, 0.f};
#pragma unroll
        for (int ks = 0; ks < K / 32; ++ks) {
            bf16x8 b = *(const bf16x8*)&Wp[(size_t)((ks * 4 + lg) * N + col) * 8];
#pragma unroll
            for (int rt = 0; rt < 4; ++rt) {
                bf16x8 a = *(const bf16x8*)&AL[(rt * 16 + lr) * lda + ks * 32 + lg * 8];
                acc[rt] = __builtin_amdgcn_mfma_f32_16x16x32_bf16(a, b, acc[rt], 0, 0, 0);
            }
        }
#pragma unroll
        for (int rt = 0; rt < 4; ++rt)
#pragma unroll
            for (int i = 0; i < 4; ++i)
                ep(rt * 16 + lg * 4 + i, col, acc[rt][i]);
    }
}

// ================= fused VAE chain (1 block) =================
__global__ __launch_bounds__(256) void fused_vae_kernel(
    const u16* __restrict__ pr0b, const float* __restrict__ eps,
    const u16* __restrict__ Wa1p, const float* __restrict__ ba1,
    const u16* __restrict__ Wa2p, const float* __restrict__ ba2,
    const u16* __restrict__ Wmulvp, const float* __restrict__ bmu, const float* __restrict__ blv,
    const u16* __restrict__ Wn1p, const float* __restrict__ bn1,
    const u16* __restrict__ Wn2p, const float* __restrict__ bn2,
    float* __restrict__ pr_o, float* __restrict__ mu_o, float* __restrict__ lv_o,
    float* __restrict__ z_o, u16* __restrict__ zbf, u16* __restrict__ g2bb) {
    __shared__ u16 P[64 * 136];
    __shared__ u16 T[64 * 272];
    __shared__ u16 Z[64 * 72];
    float* MVf = (float*)T;
    int t = threadIdx.x;
    for (int idx = t; idx < 8192; idx += 256) {
        int g = idx >> 7, c = idx & 127;
        P[g * 136 + c] = pr0b[idx];
    }
    __syncthreads();
    mm64<128, 256>(P, 136, Wa1p, [&](int row, int col, float v) {
        T[row * 272 + col] = f2b(fmaxf(v + ba1[col], 0.f));
    });
    __syncthreads();
    mm64<256, 128>(T, 272, Wa2p, [&](int row, int col, float v) {
        v += ba2[col];
        pr_o[row * 128 + col] = v;
        P[row * 136 + col] = f2b(v);
    });
    __syncthreads();
    mm64<128, 128>(P, 136, Wmulvp, [&](int row, int col, float v) {
        v += (col < 64) ? bmu[col] : blv[col - 64];
        MVf[row * 136 + col] = v;
        if (col < 64) mu_o[row * 64 + col] = v;
        else lv_o[row * 64 + (col - 64)] = v;
    });
    __syncthreads();
    for (int idx = t; idx < 4096; idx += 256) {
        int g = idx >> 6, c = idx & 63;
        float m = MVf[g * 136 + c], lvv = MVf[g * 136 + 64 + c];
        float zv = fmaf(eps[idx], __expf(0.5f * lvv), m);
        z_o[idx] = zv;
        u16 zb16 = f2b(zv);
        zbf[idx] = zb16;
        Z[g * 72 + c] = zb16;
    }
    __syncthreads();
    mm64<64, 256>(Z, 72, Wn1p, [&](int row, int col, float v) {
        T[row * 272 + col] = f2b(fmaxf(v + bn1[col], 0.f));
    });
    __syncthreads();
    mm64<256, 512>(T, 272, Wn2p, [&](int row, int col, float v) {
        g2bb[row * 512 + col] = f2b(fmaxf(v + bn2[col], 0.f));
    });
}

// ================= esed0: es/ed for layer 0 from hb via precomputed w_esed =================
// 16 nodes/block: 4 waves x 4 nodes; 16-lane group per node.
__global__ __launch_bounds__(256) void esed0_kernel(const u16* __restrict__ hb,
                                                    const float* __restrict__ w,
                                                    float* __restrict__ es,
                                                    float* __restrict__ ed) {
    int t = threadIdx.x;
    int wv = t >> 6, lane = t & 63;
    int g16 = lane >> 4, l16 = lane & 15;
    int n = blockIdx.x * 16 + wv * 4 + g16;   // grid = 625 exactly covers 10000
    u16x8 v = *(const u16x8*)&hb[(size_t)n * 128 + l16 * 8];
    float ch[8];
#pragma unroll
    for (int j = 0; j < 8; ++j) ch[j] = b2f(v[j]);
    float p[8];
#pragma unroll
    for (int o = 0; o < 8; ++o) {
        const float* wo = w + o * 128 + l16 * 8;
        float s = 0.f;
#pragma unroll
        for (int j = 0; j < 8; ++j) s = fmaf(ch[j], wo[j], s);
        p[o] = s;
    }
#pragma unroll
    for (int o = 0; o < 8; ++o) {
#pragma unroll
        for (int m = 1; m < 16; m <<= 1) p[o] += __shfl_xor(p[o], m);
    }
    if (l16 < 8) {
        if (l16 < 4) es[n * 4 + l16] = p[l16];
        else ed[n * 4 + (l16 - 4)] = p[l16];
    }
}

// ====== GAT aggregation: 4 nodes/block, one-pass softmax; epilogue computes next-layer es/ed ======
__global__ __launch_bounds__(256) void gat_agg_kernel(const u16* __restrict__ xhb,
                               const float* __restrict__ es_in, const float* __restrict__ ed_in,
                               const int* __restrict__ cursor, const int* __restrict__ csr_src,
                               const float* __restrict__ bg, float* __restrict__ h,
                               u16* __restrict__ hb,
                               const float* __restrict__ w_next,
                               float* __restrict__ es_out, float* __restrict__ ed_out) {
    __shared__ float aL[4][64][4];
    __shared__ int sL[4][64];
    int wv = threadIdx.x >> 6, lane = threadIdx.x & 63;
    int n = blockIdx.x * 4 + wv;          // grid = N_NODES/4 exactly
    int deg = cursor[n];                  // 1..64
    const float4 ed4 = ((const float4*)ed_in)[n];
    const float edh[4] = {ed4.x, ed4.y, ed4.z, ed4.w};
    float ex0 = 0.f, ex1 = 0.f, ex2 = 0.f, ex3 = 0.f;
    if (lane < deg) {
        int sj = csr_src[(n << 6) + lane];
        sL[wv][lane] = sj;
        const float4 e4 = ((const float4*)es_in)[sj];
        const float ev[4] = {e4.x, e4.y, e4.z, e4.w};
        float exv[4];
#pragma unroll
        for (int hh = 0; hh < 4; ++hh) {
            float e = ev[hh] + edh[hh];
            e = e > 0.f ? e : 0.2f * e;        // leaky relu
            e = fminf(e, 80.f);                 // overflow guard
            exv[hh] = __expf(e);                // max cancels exactly in softmax
        }
        *(float4*)&aL[wv][lane][0] = make_float4(exv[0], exv[1], exv[2], exv[3]);
        ex0 = exv[0]; ex1 = exv[1]; ex2 = exv[2]; ex3 = exv[3];
    }
#pragma unroll
    for (int off = 32; off; off >>= 1) {
        ex0 += __shfl_xor(ex0, off);
        ex1 += __shfl_xor(ex1, off);
        ex2 += __shfl_xor(ex2, off);
        ex3 += __shfl_xor(ex3, off);
    }
    __syncthreads();   // all 4 waves' aL/sL slices visible
    int head = lane >> 4, c0 = (lane & 15) * 8;
    float den = (head == 0) ? ex0 : (head == 1) ? ex1 : (head == 2) ? ex2 : ex3;
    float acc[8] = {0.f, 0.f, 0.f, 0.f, 0.f, 0.f, 0.f, 0.f};
    const u16* xb_h = xhb + head * 128 + c0;
    int j2 = 0;
    for (; j2 + 2 <= deg; j2 += 2) {
        int s0 = sL[wv][j2], s1 = sL[wv][j2 + 1];
        float al0 = aL[wv][j2][head], al1 = aL[wv][j2 + 1][head];
        u16x8 v0 = *(const u16x8*)&xb_h[(size_t)s0 * 512];
        u16x8 v1 = *(const u16x8*)&xb_h[(size_t)s1 * 512];
#pragma unroll
        for (int m = 0; m < 8; ++m) acc[m] = fmaf(al0, b2f(v0[m]), acc[m]);
#pragma unroll
        for (int m = 0; m < 8; ++m) acc[m] = fmaf(al1, b2f(v1[m]), acc[m]);
    }
    if (j2 < deg) {
        int s0 = sL[wv][j2];
        float al0 = aL[wv][j2][head];
        u16x8 v0 = *(const u16x8*)&xb_h[(size_t)s0 * 512];
#pragma unroll
        for (int m = 0; m < 8; ++m) acc[m] = fmaf(al0, b2f(v0[m]), acc[m]);
    }
    float rden = 1.f / den;
#pragma unroll
    for (int m = 0; m < 8; ++m) {
        float v = acc[m] * rden;
        v += __shfl_xor(v, 16);
        v += __shfl_xor(v, 32);
        acc[m] = v;
    }
    if (lane < 16) {
        float o8[8];
        u16x8 b8;
#pragma unroll
        for (int m = 0; m < 8; ++m) {
            int c = lane * 8 + m;
            float o = acc[m] * 0.25f + bg[c];
            o = fmaxf(o, 0.f);
            float hn = h[(size_t)n * 128 + c] + o;
            o8[m] = hn;
            b8[m] = f2b(hn);
        }
        *(float4*)&h[(size_t)n * 128 + lane * 8] = make_float4(o8[0], o8[1], o8[2], o8[3]);
        *(float4*)&h[(size_t)n * 128 + lane * 8 + 4] = make_float4(o8[4], o8[5], o8[6], o8[7]);
        *(u16x8*)&hb[(size_t)n * 128 + lane * 8] = b8;
        // next layer's es/ed from the fresh h row (double-buffered -> no race)
        if (w_next) {
            float p[8];
#pragma unroll
            for (int o = 0; o < 8; ++o) {
                const float* wo = w_next + o * 128 + lane * 8;
                float s = 0.f;
#pragma unroll
                for (int j = 0; j < 8; ++j) s = fmaf(o8[j], wo[j], s);
                p[o] = s;
            }
#pragma unroll
            for (int o = 0; o < 8; ++o) {
#pragma unroll
                for (int m = 1; m < 16; m <<= 1) p[o] += __shfl_xor(p[o], m);
            }
            if (lane < 8) {
                if (lane < 4) es_out[n * 4 + lane] = p[lane];
                else ed_out[n * 4 + (lane - 4)] = p[lane];
            }
        }
    }
}

// ================= pooling: one block per graph, 1024 threads =================
__global__ __launch_bounds__(1024) void pool_kernel2(const float* __restrict__ h,
                                                     const int* __restrict__ batch,
                                                     u16* __restrict__ pr0b) {
    __shared__ float red[8][128];
    int g = blockIdx.x;
    int t = threadIdx.x;
    int c = t & 127, rg = t >> 7;
    int lo = 0, hi = N_NODES;
    while (lo < hi) { int m = (lo + hi) >> 1; if (batch[m] < g) lo = m + 1; else hi = m; }
    int s = lo;
    lo = 0; hi = N_NODES;
    while (lo < hi) { int m = (lo + hi) >> 1; if (batch[m] < g + 1) lo = m + 1; else hi = m; }
    int e = lo;
    float acc = 0.f;
    for (int n = s + rg; n < e; n += 8) acc += h[(size_t)n * HID + c];
    red[rg][c] = acc;
    __syncthreads();
    if (rg == 0) {
        float sum = ((red[0][c] + red[1][c]) + (red[2][c] + red[3][c])) +
                    ((red[4][c] + red[5][c]) + (red[6][c] + red[7][c]));
        float cn = fmaxf((float)(e - s), 1.f);
        pr0b[g * HID + c] = f2b(sum / cn);
    }
}

// ================= fused edge + reaction MLPs via MFMA, 64 rows per block =================
__global__ __launch_bounds__(256) void edge_react_mfma(
    const u16* __restrict__ zb, const u16* __restrict__ nb,
    const int* __restrict__ pi, const int* __restrict__ pj,
    const u16* __restrict__ We1p, const float* __restrict__ be1,
    const u16* __restrict__ We2p, const float* __restrict__ be2,
    const float* __restrict__ We3, const float* __restrict__ be3,
    const u16* __restrict__ Wr1p, const float* __restrict__ br1,
    const float* __restrict__ Wr2, const float* __restrict__ br2,
    float* __restrict__ edgep, float* __restrict__ react) {
    __shared__ u16 inA[64 * 200];
    __shared__ u16 h1A[64 * 136];
    __shared__ u16 rhA[64 * 68];
    int t = threadIdx.x, w = t >> 6, l = t & 63, lr = l & 15, lg = l >> 4;
    int b = blockIdx.y, p0 = blockIdx.x * 64;
    for (int u = t; u < 1536; u += 256) {
        int r = u / 24, c8 = (u % 24) * 8;
        int p = min(p0 + r, NPAIR - 1);
        const u16* src;
        if (c8 < 64) src = zb + b * 64 + c8;
        else if (c8 < 128) src = nb + b * NODESF + pi[p] * 64 + (c8 - 64);
        else src = nb + b * NODESF + pj[p] * 64 + (c8 - 128);
        *(u16x8*)&inA[r * 200 + c8] = *(const u16x8*)src;
    }
    __syncthreads();
    f32x4 a1[4][2];
#pragma unroll
    for (int rt = 0; rt < 4; ++rt)
#pragma unroll
        for (int ct = 0; ct < 2; ++ct) a1[rt][ct] = (f32x4){0.f, 0.f, 0.f, 0.f};
#pragma unroll
    for (int ks = 0; ks < 6; ++ks) {
        bf16x8 af[4], bf_[2];
#pragma unroll
        for (int rt = 0; rt < 4; ++rt)
            af[rt] = *(const bf16x8*)&inA[(rt * 16 + lr) * 200 + ks * 32 + lg * 8];
#pragma unroll
        for (int ct = 0; ct < 2; ++ct) {
            int col = w * 32 + ct * 16 + lr;
            bf_[ct] = *(const bf16x8*)&We1p[(size_t)((ks * 4 + lg) * 128 + col) * 8];
        }
#pragma unroll
        for (int rt = 0; rt < 4; ++rt)
#pragma unroll
            for (int ct = 0; ct < 2; ++ct)
                a1[rt][ct] = __builtin_amdgcn_mfma_f32_16x16x32_bf16(af[rt], bf_[ct], a1[rt][ct], 0, 0, 0);
    }
    f32x4 r1[4];
#pragma unroll
    for (int rt = 0; rt < 4; ++rt) r1[rt] = (f32x4){0.f, 0.f, 0.f, 0.f};
#pragma unroll
    for (int ks = 0; ks < 4; ++ks) {
        bf16x8 af[4];
#pragma unroll
        for (int rt = 0; rt < 4; ++rt)
            af[rt] = *(const bf16x8*)&inA[(rt * 16 + lr) * 200 + 64 + ks * 32 + lg * 8];
        int col = w * 16 + lr;
        bf16x8 bf_ = *(const bf16x8*)&Wr1p[(size_t)((ks * 4 + lg) * 64 + col) * 8];
#pragma unroll
        for (int rt = 0; rt < 4; ++rt)
            r1[rt] = __builtin_amdgcn_mfma_f32_16x16x32_bf16(af[rt], bf_, r1[rt], 0, 0, 0);
    }
#pragma unroll
    for (int rt = 0; rt < 4; ++rt)
#pragma unroll
        for (int ct = 0; ct < 2; ++ct) {
            int col = w * 32 + ct * 16 + lr;
            float bia = be1[col];
#pragma unroll
            for (int i = 0; i < 4; ++i) {
                int row = rt * 16 + lg * 4 + i;
                h1A[row * 136 + col] = f2b(fmaxf(a1[rt][ct][i] + bia, 0.f));
            }
        }
#pragma unroll
    for (int rt = 0; rt < 4; ++rt) {
        int col = w * 16 + lr;
        float bia = br1[col];
#pragma unroll
        for (int i = 0; i < 4; ++i) {
            int row = rt * 16 + lg * 4 + i;
            rhA[row * 68 + col] = f2b(fmaxf(r1[rt][i] + bia, 0.f));
        }
    }
    __syncthreads();
    f32x4 a2[4];
#pragma unroll
    for (int rt = 0; rt < 4; ++rt) a2[rt] = (f32x4){0.f, 0.f, 0.f, 0.f};
#pragma unroll
    for (int ks = 0; ks < 4; ++ks) {
        bf16x8 af[4];
#pragma unroll
        for (int rt = 0; rt < 4; ++rt)
            af[rt] = *(const bf16x8*)&h1A[(rt * 16 + lr) * 136 + ks * 32 + lg * 8];
        int col = w * 16 + lr;
        bf16x8 bf_ = *(const bf16x8*)&We2p[(size_t)((ks * 4 + lg) * 64 + col) * 8];
#pragma unroll
        for (int rt = 0; rt < 4; ++rt)
            a2[rt] = __builtin_amdgcn_mfma_f32_16x16x32_bf16(af[rt], bf_, a2[rt], 0, 0, 0);
    }
    u16* h2A = inA;
#pragma unroll
    for (int rt = 0; rt < 4; ++rt) {
        int col = w * 16 + lr;
        float bia = be2[col];
#pragma unroll
        for (int i = 0; i < 4; ++i) {
            int row = rt * 16 + lg * 4 + i;
            h2A[row * 68 + col] = f2b(fmaxf(a2[rt][i] + bia, 0.f));
        }
    }
    __syncthreads();
    int r = t >> 2, sub = t & 3;
    int p = p0 + r;
    float acc3 = 0.f;
#pragma unroll
    for (int kk = 0; kk < 16; ++kk) {
        int c = sub * 16 + kk;
        acc3 = fmaf(b2f(h2A[r * 68 + c]), We3[c], acc3);
    }
    acc3 += __shfl_xor(acc3, 1);
    acc3 += __shfl_xor(acc3, 2);
    if (sub == 0 && p < NPAIR)
        edgep[b * NPAIR + p] = 1.f / (1.f + __expf(-(acc3 + be3[0])));
    float lg6[6] = {0.f, 0.f, 0.f, 0.f, 0.f, 0.f};
#pragma unroll
    for (int kk = 0; kk < 16; ++kk) {
        int c = sub * 16 + kk;
        float v = b2f(rhA[r * 68 + c]);
#pragma unroll
        for (int m = 0; m < 6; ++m) lg6[m] = fmaf(v, Wr2[c * 6 + m], lg6[m]);
    }
#pragma unroll
    for (int m = 0; m < 6; ++m) {
        lg6[m] += __shfl_xor(lg6[m], 1);
        lg6[m] += __shfl_xor(lg6[m], 2);
    }
    if (sub == 0 && p < NPAIR) {
        float mx = -3.4e38f;
#pragma unroll
        for (int m = 0; m < 6; ++m) { lg6[m] += br2[m]; mx = fmaxf(mx, lg6[m]); }
        float s = 0.f;
        float ex[6];
#pragma unroll
        for (int m = 0; m < 6; ++m) { ex[m] = __expf(lg6[m] - mx); s += ex[m]; }
        float rs = 1.f / s;
#pragma unroll
        for (int m = 0; m < 6; ++m) react[(size_t)(b * NPAIR + p) * 6 + m] = ex[m] * rs;
    }
}

// ================= launch =================
extern "C" void kernel_launch(void* const* d_in, const int* in_sizes, int n_in,
                              void* d_out, int out_size, void* d_ws, size_t ws_size,
                              hipStream_t stream) {
    const float* x     = (const float*)d_in[0];
    const int*   ei    = (const int*)d_in[1];
    const int*   batch = (const int*)d_in[2];
    const float* eps   = (const float*)d_in[3];
    const float* We    = (const float*)d_in[4];
    const float* be    = (const float*)d_in[5];
    const float* Wg    = (const float*)d_in[6];
    const float* ags   = (const float*)d_in[7];
    const float* agd   = (const float*)d_in[8];
    const float* bg    = (const float*)d_in[9];
    const float* Wa1   = (const float*)d_in[10];
    const float* ba1   = (const float*)d_in[11];
    const float* Wa2   = (const float*)d_in[12];
    const float* ba2   = (const float*)d_in[13];
    const float* Wmu   = (const float*)d_in[14];
    const float* bmu   = (const float*)d_in[15];
    const float* Wlv   = (const float*)d_in[16];
    const float* blv   = (const float*)d_in[17];
    const float* Wn1   = (const float*)d_in[18];
    const float* bn1   = (const float*)d_in[19];
    const float* Wn2   = (const float*)d_in[20];
    const float* bn2   = (const float*)d_in[21];
    const float* Wn3   = (const float*)d_in[22];
    const float* bn3   = (const float*)d_in[23];
    const float* We1   = (const float*)d_in[24];
    const float* be1   = (const float*)d_in[25];
    const float* We2   = (const float*)d_in[26];
    const float* be2   = (const float*)d_in[27];
    const float* We3   = (const float*)d_in[28];
    const float* be3   = (const float*)d_in[29];
    const float* Wr1   = (const float*)d_in[30];
    const float* br1   = (const float*)d_in[31];
    const float* Wr2   = (const float*)d_in[32];
    const float* br2   = (const float*)d_in[33];

    float* out = (float*)d_out;
    float* mu_o    = out;
    float* lv_o    = out + 4096;
    float* z_o     = out + 8192;
    float* pr_o    = out + 12288;
    float* nodep_o = out + 20480;
    float* edgep_o = out + 225280;
    float* react_o = out + 303680;

    float* F = (float*)d_ws;
    size_t o = 0;
    float* h   = F + o; o += (size_t)N_NODES * HID;
    float* es0 = F + o; o += (size_t)N_NODES * 4;
    float* ed0 = F + o; o += (size_t)N_NODES * 4;
    float* es1 = F + o; o += (size_t)N_NODES * 4;
    float* ed1 = F + o; o += (size_t)N_NODES * 4;
    float* wesed = F + o; o += PACK_W;          // 3*2*4*128
    u16* U = (u16*)(F + o);
    size_t uo = 0;
    u16* hb     = U + uo; uo += (size_t)N_NODES * HID;
    u16* xb     = U + uo; uo += (size_t)N_NODES * NF;
    u16* xhb    = U + uo; uo += (size_t)N_NODES * HC;
    u16* zbf    = U + uo; uo += 4096;
    u16* nbf    = U + uo; uo += 64 * NODESF;
    u16* pr0b   = U + uo; uo += 64 * HID;
    u16* g2bb   = U + uo; uo += 64 * 512;
    u16* Wgp    = U + uo; uo += (size_t)3 * 16 * 512 * 8;
    u16* We1p   = U + uo; uo += 24 * 128 * 8;
    u16* We2p   = U + uo; uo += 16 * 64 * 8;
    u16* Wr1p   = U + uo; uo += 16 * 64 * 8;
    u16* Wa1p   = U + uo; uo += 16 * 256 * 8;
    u16* Wa2p   = U + uo; uo += 32 * 128 * 8;
    u16* Wmulvp = U + uo; uo += 16 * 128 * 8;
    u16* Wn1p   = U + uo; uo += 8 * 256 * 8;
    u16* Wn2p   = U + uo; uo += 32 * 512 * 8;
    u16* Wn3p   = U + uo; uo += (size_t)64 * 3200 * 8;
    u16* Wep    = U + uo; uo += 8 * 128 * 8;
    if (uo & 7) uo += 8 - (uo & 7);
    int* I = (int*)(U + uo);
    int* piA     = I;
    int* pjA     = piA + NPAIR;
    int* cursor  = pjA + NPAIR;                 // zeroed (N_NODES)
    int* csr_src = cursor + N_NODES;            // N_NODES * DEG_CAP

    // zero cursor every call — graph replays don't re-poison
    hipMemsetAsync(cursor, 0, (size_t)N_NODES * sizeof(int), stream);

    PackArgs pa;
    pa.src[0] = Wg;               pa.dst[0] = Wgp;
    pa.src[1] = Wg + 65536;       pa.dst[1] = Wgp + 65536;
    pa.src[2] = Wg + 131072;      pa.dst[2] = Wgp + 131072;
    pa.src[3] = We1;              pa.dst[3] = We1p;
    pa.src[4] = We2;              pa.dst[4] = We2p;
    pa.src[5] = Wr1;              pa.dst[5] = Wr1p;
    pa.src[6] = Wa1;              pa.dst[6] = Wa1p;
    pa.src[7] = Wa2;              pa.dst[7] = Wa2p;
    pa.src[8] = Wmu;              pa.dst[8] = Wmulvp;
    pa.src[9] = Wlv;              pa.dst[9] = Wmulvp;
    pa.src[10] = Wn1;             pa.dst[10] = Wn1p;
    pa.src[11] = Wn2;             pa.dst[11] = Wn2p;
    pa.src[12] = Wn3;             pa.dst[12] = Wn3p;
    pa.src[13] = We;              pa.dst[13] = Wep;
    pa.src[14] = x;               pa.dst[14] = xb;
    // pack + pairs + bucket CSR fill + w_esed precompute in one launch
    pack_all_kernel<<<(PACK_GRID_TOTAL + 255) / 256, 256, 0, stream>>>(
        pa, piA, pjA, ei, cursor, csr_src, Wg, ags, agd, wesed);

    // h = relu(x @ We + be)
    gemm_mh_kernel<64, 128, 128, true, true, true>
        <<<dim3((N_NODES + 63) / 64, 1), 256, 0, stream>>>(xb, Wep, be, hb, h);

    // layer-0 es/ed from hb via w_esed
    esed0_kernel<<<N_NODES / 16, 256, 0, stream>>>(hb, wesed, es0, ed0);

    // 3 GAT layers; gat_agg epilogue emits next layer's es/ed (double-buffered)
    float* esA = es0; float* edA = ed0;
    float* esB = es1; float* edB = ed1;
    for (int l = 0; l < 3; ++l) {
        gemm_mh_kernel<128, 512, 64, false, false, false>
            <<<dim3((N_NODES + 63) / 64, 8), 256, 0, stream>>>(
                hb, Wgp + (size_t)l * 65536, nullptr, xhb, nullptr);
        const float* w_next = (l < 2) ? (wesed + (size_t)(l + 1) * 1024) : nullptr;
        gat_agg_kernel<<<N_NODES / 4, 256, 0, stream>>>(
            xhb, esA, edA, cursor, csr_src, bg + l * HID, h, hb, w_next, esB, edB);
        float* te = esA; esA = esB; esB = te;
        float* td = edA; edA = edB; edB = td;
    }

    // pooling
    pool_kernel2<<<N_GRAPHS, 1024, 0, stream>>>(h, batch, pr0b);

    // fused VAE chain
    fused_vae_kernel<<<1, 256, 0, stream>>>(
        pr0b, eps, Wa1p, ba1, Wa2p, ba2, Wmulvp, bmu, blv,
        Wn1p, bn1, Wn2p, bn2, pr_o, mu_o, lv_o, z_o, zbf, g2bb);

    // nodes = sigmoid(g2 @ Wn3 + bn3) + raw bf16
    gemm64_kernel<512, 4, 2, false><<<200, 256, 0, stream>>>(
        g2bb, Wn3p, bn3, nullptr, nodep_o, nullptr, nbf, 3200);

    // fused edge + reaction MLPs
    edge_react_mfma<<<dim3(20, 64), 256, 0, stream>>>(
        zbf, nbf, piA, pjA, We1p, be1, We2p, be2, We3, be3,
        Wr1p, br1, Wr2, br2, edgep_o, react_o);
}

// Round 14
// 220.008 us; speedup vs baseline: 1.0710x; 1.0710x over previous
//
#include <hip/hip_runtime.h>
#include <cstddef>

#define N_NODES 10000
#define N_EDGES 160000
#define E_TOT   170000
#define N_GRAPHS 64
#define NF 64
#define HID 128
#define HC 512
#define LAT 64
#define MAXN 50
#define NPAIR 1225
#define NODESF 3200
#define DEG_CAP 64

typedef __attribute__((ext_vector_type(8))) short bf16x8;
typedef __attribute__((ext_vector_type(8))) unsigned short u16x8;
typedef __attribute__((ext_vector_type(4))) float f32x4;
typedef unsigned short u16;
typedef unsigned int u32;

__device__ __forceinline__ u16 f2b(float f) {
    u32 u = __float_as_uint(f);
    u32 r = (u + 0x7fffu + ((u >> 16) & 1u)) >> 16;
    return (u16)r;
}
__device__ __forceinline__ float b2f(u16 v) {
    return __uint_as_float(((u32)v) << 16);
}

// ====== pack_all: weights -> bf16 B-fragment layout, x -> bf16, + pairs + bucket CSR fill ======
struct PackArgs {
    const float* src[15];
    u16* dst[15];
};
#define PACK_TOTAL 344192
#define PACK_GRID_TOTAL (PACK_TOTAL + NPAIR + E_TOT)
__global__ void pack_all_kernel(PackArgs pa, int* __restrict__ pi, int* __restrict__ pj,
                                const int* __restrict__ ei, int* __restrict__ cursor,
                                int* __restrict__ csr_src) {
    int idx = blockIdx.x * 256 + threadIdx.x;
    if (idx >= PACK_GRID_TOTAL) return;
    if (idx >= PACK_TOTAL) {
        int r = idx - PACK_TOTAL;
        if (r < NPAIR) {
            int i = 0, off = 0;
            while (off + (MAXN - 1 - i) <= r) { off += MAXN - 1 - i; ++i; }
            pi[r] = i;
            pj[r] = i + 1 + (r - off);
        } else {
            // bucket CSR fill: order within bucket irrelevant
            int e = r - NPAIR;  // < E_TOT
            int s, d;
            if (e < N_EDGES) { s = ei[e]; d = ei[N_EDGES + e]; }
            else { s = e - N_EDGES; d = s; }
            int pos = atomicAdd(&cursor[d], 1);
            csr_src[(d << 6) + pos] = s;   // DEG_CAP=64; max real degree ~40 (verified R9-R12)
        }
        return;
    }
    const int base[16] = {0, 8192, 16384, 24576, 27648, 28672, 29696, 33792, 37888,
                          38912, 39936, 41984, 58368, 263168, 264192, 344192};
    const int Ns[15]   = {512, 512, 512, 128, 64, 64, 256, 128, 64, 64, 256, 512, 3200, 128, 0};
    const int dNs[15]  = {512, 512, 512, 128, 64, 64, 256, 128, 128, 128, 256, 512, 3200, 128, 0};
    const int coff[15] = {0, 0, 0, 0, 0, 0, 0, 0, 0, 64, 0, 0, 0, 0, 0};
    int s = 0;
    while (idx >= base[s + 1]) ++s;
    int i = idx - base[s];
    const float* sp = pa.src[s];
    u16* dp = pa.dst[s];
    if (s == 14) {
        u16x8 o;
#pragma unroll
        for (int j = 0; j < 8; ++j) o[j] = f2b(sp[(size_t)i * 8 + j]);
        *(u16x8*)&dp[(size_t)i * 8] = o;
        return;
    }
    int N = Ns[s];
    int g = i / N, n = i - g * N;
    u16x8 o;
#pragma unroll
    for (int j = 0; j < 8; ++j) o[j] = f2b(sp[(size_t)(g * 8 + j) * N + n]);
    *(u16x8*)&dp[((size_t)g * dNs[s] + n + coff[s]) * 8] = o;
}

// ================= gemm_mh: M-large MFMA GEMM, 64 rows x CB cols per block =================
template<int K, int NT, int CB, bool BIAS, bool RELU, bool F32OUT>
__global__ __launch_bounds__(256) void gemm_mh_kernel(const u16* __restrict__ A,
                                                      const u16* __restrict__ Wp,
                                                      const float* __restrict__ bias,
                                                      u16* __restrict__ bo,
                                                      float* __restrict__ fo) {
    constexpr int CT = CB / 64;   // col-tiles per wave
    __shared__ u16 AL[64 * (K + 8)];
    int t = threadIdx.x, w = t >> 6, l = t & 63, lr = l & 15, lg = l >> 4;
    int rb = blockIdx.x * 64, j0 = blockIdx.y * CB;
    for (int u = t; u < 64 * (K / 8); u += 256) {
        int r = u / (K / 8), c8 = (u % (K / 8)) * 8;
        int row = min(rb + r, N_NODES - 1);
        *(u16x8*)&AL[r * (K + 8) + c8] = *(const u16x8*)&A[(size_t)row * K + c8];
    }
    __syncthreads();
    f32x4 acc[4][CT];
#pragma unroll
    for (int rt = 0; rt < 4; ++rt)
#pragma unroll
        for (int ct = 0; ct < CT; ++ct) acc[rt][ct] = (f32x4){0.f, 0.f, 0.f, 0.f};
#pragma unroll
    for (int ks = 0; ks < K / 32; ++ks) {
        bf16x8 a[4], b[CT];
#pragma unroll
        for (int rt = 0; rt < 4; ++rt)
            a[rt] = *(const bf16x8*)&AL[(rt * 16 + lr) * (K + 8) + ks * 32 + lg * 8];
#pragma unroll
        for (int ct = 0; ct < CT; ++ct) {
            int col = j0 + w * (CB / 4) + ct * 16 + lr;
            b[ct] = *(const bf16x8*)&Wp[(size_t)((ks * 4 + lg) * NT + col) * 8];
        }
#pragma unroll
        for (int rt = 0; rt < 4; ++rt)
#pragma unroll
            for (int ct = 0; ct < CT; ++ct)
                acc[rt][ct] = __builtin_amdgcn_mfma_f32_16x16x32_bf16(a[rt], b[ct], acc[rt][ct], 0, 0, 0);
    }
#pragma unroll
    for (int rt = 0; rt < 4; ++rt)
#pragma unroll
        for (int ct = 0; ct < CT; ++ct) {
            int col = j0 + w * (CB / 4) + ct * 16 + lr;
            float bj = BIAS ? bias[col] : 0.f;
#pragma unroll
            for (int i = 0; i < 4; ++i) {
                int row = rb + rt * 16 + lg * 4 + i;
                if (row < N_NODES) {
                    float v = acc[rt][ct][i] + bj;
                    if (RELU) v = fmaxf(v, 0.f);
                    bo[(size_t)row * NT + col] = f2b(v);
                    if (F32OUT) fo[(size_t)row * NT + col] = v;
                }
            }
        }
}

// ================= gemm64: M=64 skinny MFMA GEMM with intra-block split-K =================
template<int K, int G, int ACT, bool SPLIT>
__global__ __launch_bounds__(256) void gemm64_kernel(const u16* __restrict__ A,
                                                     const u16* __restrict__ Wp,
                                                     const float* __restrict__ bias,
                                                     const float* __restrict__ bias2,
                                                     float* __restrict__ fo,
                                                     float* __restrict__ fo2,
                                                     u16* __restrict__ bo, int N) {
    constexpr int CG = 4 / G, NB = CG * 16, Kc = K / G, KS = Kc / 32;
    constexpr int ABYTES = 64 * (K + 8) * 2;
    constexpr int LDSB = (ABYTES > 16384) ? ABYTES : 16384;
    __shared__ float LDSf[LDSB / 4];
    u16* AL = (u16*)LDSf;
    float* RB = LDSf;
    int t = threadIdx.x, w = t >> 6, l = t & 63, lr = l & 15, lg = l >> 4;
    for (int u = t; u < 64 * (K / 8); u += 256) {
        int r = u / (K / 8), c8 = (u % (K / 8)) * 8;
        *(u16x8*)&AL[r * (K + 8) + c8] = *(const u16x8*)&A[(size_t)r * K + c8];
    }
    __syncthreads();
    int kg = w % G, cg = w / G;
    int col = blockIdx.x * NB + cg * 16 + lr;
    f32x4 acc[4];
#pragma unroll
    for (int rt = 0; rt < 4; ++rt) acc[rt] = (f32x4){0.f, 0.f, 0.f, 0.f};
#pragma unroll
    for (int ks = 0; ks < KS; ++ks) {
        int k0 = kg * Kc + ks * 32;
        bf16x8 b = *(const bf16x8*)&Wp[(size_t)(((k0 >> 3) + lg) * N + col) * 8];
#pragma unroll
        for (int rt = 0; rt < 4; ++rt) {
            bf16x8 a = *(const bf16x8*)&AL[(rt * 16 + lr) * (K + 8) + k0 + lg * 8];
            acc[rt] = __builtin_amdgcn_mfma_f32_16x16x32_bf16(a, b, acc[rt], 0, 0, 0);
        }
    }
    __syncthreads();
#pragma unroll
    for (int rt = 0; rt < 4; ++rt)
#pragma unroll
        for (int i = 0; i < 4; ++i)
            RB[w * 1024 + (rt * 16 + lg * 4 + i) * 16 + lr] = acc[rt][i];
    __syncthreads();
    for (int e = t; e < 64 * NB; e += 256) {
        int row = e / NB, cb = e - row * NB;
        int cg2 = cb >> 4, cl = cb & 15;
        float s = 0.f;
#pragma unroll
        for (int kg2 = 0; kg2 < G; ++kg2)
            s += RB[(cg2 * G + kg2) * 1024 + row * 16 + cl];
        int c = blockIdx.x * NB + cb;
        float bj;
        if (SPLIT) bj = (c < 64) ? bias[c] : bias2[c - 64];
        else bj = bias[c];
        float v = s + bj;
        if (ACT == 1) v = fmaxf(v, 0.f);
        if (bo) bo[(size_t)row * N + c] = f2b(v);
        if (SPLIT) {
            if (c < 64) fo[row * 64 + c] = v;
            else fo2[row * 64 + (c - 64)] = v;
        } else if (fo) {
            float ov = (ACT == 2) ? 1.f / (1.f + __expf(-v)) : v;
            fo[(size_t)row * N + c] = ov;
        }
    }
}

// ================= mm64: in-kernel M=64 MFMA sub-GEMM (4 waves, N/64 col passes) =================
template<int K, int N, typename EP>
__device__ __forceinline__ void mm64(const u16* __restrict__ AL, int lda,
                                     const u16* __restrict__ Wp, EP ep) {
    int t = threadIdx.x, w = t >> 6, l = t & 63, lr = l & 15, lg = l >> 4;
#pragma unroll
    for (int p = 0; p < N / 64; ++p) {
        int col = p * 64 + w * 16 + lr;
        f32x4 acc[4];
#pragma unroll
        for (int rt = 0; rt < 4; ++rt) acc[rt] = (f32x4){0.f, 0.f, 0.f, 0.f};
#pragma unroll
        for (int ks = 0; ks < K / 32; ++ks) {
            bf16x8 b = *(const bf16x8*)&Wp[(size_t)((ks * 4 + lg) * N + col) * 8];
#pragma unroll
            for (int rt = 0; rt < 4; ++rt) {
                bf16x8 a = *(const bf16x8*)&AL[(rt * 16 + lr) * lda + ks * 32 + lg * 8];
                acc[rt] = __builtin_amdgcn_mfma_f32_16x16x32_bf16(a, b, acc[rt], 0, 0, 0);
            }
        }
#pragma unroll
        for (int rt = 0; rt < 4; ++rt)
#pragma unroll
            for (int i = 0; i < 4; ++i)
                ep(rt * 16 + lg * 4 + i, col, acc[rt][i]);
    }
}

// ================= fused VAE chain (1 block) =================
__global__ __launch_bounds__(256) void fused_vae_kernel(
    const u16* __restrict__ pr0b, const float* __restrict__ eps,
    const u16* __restrict__ Wa1p, const float* __restrict__ ba1,
    const u16* __restrict__ Wa2p, const float* __restrict__ ba2,
    const u16* __restrict__ Wmulvp, const float* __restrict__ bmu, const float* __restrict__ blv,
    const u16* __restrict__ Wn1p, const float* __restrict__ bn1,
    const u16* __restrict__ Wn2p, const float* __restrict__ bn2,
    float* __restrict__ pr_o, float* __restrict__ mu_o, float* __restrict__ lv_o,
    float* __restrict__ z_o, u16* __restrict__ zbf, u16* __restrict__ g2bb) {
    __shared__ u16 P[64 * 136];
    __shared__ u16 T[64 * 272];
    __shared__ u16 Z[64 * 72];
    float* MVf = (float*)T;
    int t = threadIdx.x;
    for (int idx = t; idx < 8192; idx += 256) {
        int g = idx >> 7, c = idx & 127;
        P[g * 136 + c] = pr0b[idx];
    }
    __syncthreads();
    mm64<128, 256>(P, 136, Wa1p, [&](int row, int col, float v) {
        T[row * 272 + col] = f2b(fmaxf(v + ba1[col], 0.f));
    });
    __syncthreads();
    mm64<256, 128>(T, 272, Wa2p, [&](int row, int col, float v) {
        v += ba2[col];
        pr_o[row * 128 + col] = v;
        P[row * 136 + col] = f2b(v);
    });
    __syncthreads();
    mm64<128, 128>(P, 136, Wmulvp, [&](int row, int col, float v) {
        v += (col < 64) ? bmu[col] : blv[col - 64];
        MVf[row * 136 + col] = v;
        if (col < 64) mu_o[row * 64 + col] = v;
        else lv_o[row * 64 + (col - 64)] = v;
    });
    __syncthreads();
    for (int idx = t; idx < 4096; idx += 256) {
        int g = idx >> 6, c = idx & 63;
        float m = MVf[g * 136 + c], lvv = MVf[g * 136 + 64 + c];
        float zv = fmaf(eps[idx], __expf(0.5f * lvv), m);
        z_o[idx] = zv;
        u16 zb16 = f2b(zv);
        zbf[idx] = zb16;
        Z[g * 72 + c] = zb16;
    }
    __syncthreads();
    mm64<64, 256>(Z, 72, Wn1p, [&](int row, int col, float v) {
        T[row * 272 + col] = f2b(fmaxf(v + bn1[col], 0.f));
    });
    __syncthreads();
    mm64<256, 512>(T, 272, Wn2p, [&](int row, int col, float v) {
        g2bb[row * 512 + col] = f2b(fmaxf(v + bn2[col], 0.f));
    });
}

// ================= es/ed from bf16 xh =================
__global__ void esed_kernel(const u16* __restrict__ xhb, const float* __restrict__ ags,
                            const float* __restrict__ agd, float* __restrict__ es,
                            float* __restrict__ ed) {
    int wv = threadIdx.x >> 6, lane = threadIdx.x & 63;
    int n = blockIdx.x * 4 + wv;
    if (n >= N_NODES) return;
    u16x8 v = *(const u16x8*)&xhb[(size_t)n * 512 + lane * 8];
    float ps = 0.f, pd = 0.f;
#pragma unroll
    for (int j = 0; j < 8; ++j) {
        float f = b2f(v[j]);
        ps = fmaf(f, ags[lane * 8 + j], ps);
        pd = fmaf(f, agd[lane * 8 + j], pd);
    }
#pragma unroll
    for (int off = 1; off < 16; off <<= 1) {
        ps += __shfl_xor(ps, off);
        pd += __shfl_xor(pd, off);
    }
    if ((lane & 15) == 0) {
        es[n * 4 + (lane >> 4)] = ps;
        ed[n * 4 + (lane >> 4)] = pd;
    }
}

// ====== GAT aggregation: 4 nodes/block, one-pass softmax, 2x-unrolled gathers ======
__global__ __launch_bounds__(256) void gat_agg_kernel(const u16* __restrict__ xhb,
                               const float* __restrict__ es, const float* __restrict__ ed,
                               const int* __restrict__ cursor, const int* __restrict__ csr_src,
                               const float* __restrict__ bg, float* __restrict__ h,
                               u16* __restrict__ hb) {
    __shared__ float aL[4][64][4];
    __shared__ int sL[4][64];
    int wv = threadIdx.x >> 6, lane = threadIdx.x & 63;
    int n = blockIdx.x * 4 + wv;          // grid = N_NODES/4 exactly
    int deg = cursor[n];                  // 1..64
    const float4 ed4 = ((const float4*)ed)[n];
    const float edh[4] = {ed4.x, ed4.y, ed4.z, ed4.w};
    float ex0 = 0.f, ex1 = 0.f, ex2 = 0.f, ex3 = 0.f;
    if (lane < deg) {
        int sj = csr_src[(n << 6) + lane];
        sL[wv][lane] = sj;
        const float4 e4 = ((const float4*)es)[sj];
        const float ev[4] = {e4.x, e4.y, e4.z, e4.w};
        float exv[4];
#pragma unroll
        for (int hh = 0; hh < 4; ++hh) {
            float e = ev[hh] + edh[hh];
            e = e > 0.f ? e : 0.2f * e;        // leaky relu
            e = fminf(e, 80.f);                 // overflow guard
            exv[hh] = __expf(e);                // max cancels exactly in softmax
        }
        *(float4*)&aL[wv][lane][0] = make_float4(exv[0], exv[1], exv[2], exv[3]);
        ex0 = exv[0]; ex1 = exv[1]; ex2 = exv[2]; ex3 = exv[3];
    }
#pragma unroll
    for (int off = 32; off; off >>= 1) {
        ex0 += __shfl_xor(ex0, off);
        ex1 += __shfl_xor(ex1, off);
        ex2 += __shfl_xor(ex2, off);
        ex3 += __shfl_xor(ex3, off);
    }
    __syncthreads();   // all 4 waves' aL/sL slices visible
    int head = lane >> 4, c0 = (lane & 15) * 8;
    float den = (head == 0) ? ex0 : (head == 1) ? ex1 : (head == 2) ? ex2 : ex3;
    float acc[8] = {0.f, 0.f, 0.f, 0.f, 0.f, 0.f, 0.f, 0.f};
    const u16* xb_h = xhb + head * 128 + c0;
    // 2x unrolled: both loads issued before either accumulate (2 gathers in flight)
    int j2 = 0;
    for (; j2 + 2 <= deg; j2 += 2) {
        int s0 = sL[wv][j2], s1 = sL[wv][j2 + 1];
        float al0 = aL[wv][j2][head], al1 = aL[wv][j2 + 1][head];
        u16x8 v0 = *(const u16x8*)&xb_h[(size_t)s0 * 512];
        u16x8 v1 = *(const u16x8*)&xb_h[(size_t)s1 * 512];
#pragma unroll
        for (int m = 0; m < 8; ++m) acc[m] = fmaf(al0, b2f(v0[m]), acc[m]);
#pragma unroll
        for (int m = 0; m < 8; ++m) acc[m] = fmaf(al1, b2f(v1[m]), acc[m]);
    }
    if (j2 < deg) {
        int s0 = sL[wv][j2];
        float al0 = aL[wv][j2][head];
        u16x8 v0 = *(const u16x8*)&xb_h[(size_t)s0 * 512];
#pragma unroll
        for (int m = 0; m < 8; ++m) acc[m] = fmaf(al0, b2f(v0[m]), acc[m]);
    }
    float rden = 1.f / den;
#pragma unroll
    for (int m = 0; m < 8; ++m) {
        float v = acc[m] * rden;
        v += __shfl_xor(v, 16);
        v += __shfl_xor(v, 32);
        acc[m] = v;
    }
    if (lane < 16) {
        float o8[8];
        u16x8 b8;
#pragma unroll
        for (int m = 0; m < 8; ++m) {
            int c = lane * 8 + m;
            float o = acc[m] * 0.25f + bg[c];
            o = fmaxf(o, 0.f);
            float hn = h[(size_t)n * 128 + c] + o;
            o8[m] = hn;
            b8[m] = f2b(hn);
        }
        *(float4*)&h[(size_t)n * 128 + lane * 8] = make_float4(o8[0], o8[1], o8[2], o8[3]);
        *(float4*)&h[(size_t)n * 128 + lane * 8 + 4] = make_float4(o8[4], o8[5], o8[6], o8[7]);
        *(u16x8*)&hb[(size_t)n * 128 + lane * 8] = b8;
    }
}

// ================= pooling: one block per graph, 1024 threads =================
__global__ __launch_bounds__(1024) void pool_kernel2(const float* __restrict__ h,
                                                     const int* __restrict__ batch,
                                                     u16* __restrict__ pr0b) {
    __shared__ float red[8][128];
    int g = blockIdx.x;
    int t = threadIdx.x;
    int c = t & 127, rg = t >> 7;
    int lo = 0, hi = N_NODES;
    while (lo < hi) { int m = (lo + hi) >> 1; if (batch[m] < g) lo = m + 1; else hi = m; }
    int s = lo;
    lo = 0; hi = N_NODES;
    while (lo < hi) { int m = (lo + hi) >> 1; if (batch[m] < g + 1) lo = m + 1; else hi = m; }
    int e = lo;
    float acc = 0.f;
    for (int n = s + rg; n < e; n += 8) acc += h[(size_t)n * HID + c];
    red[rg][c] = acc;
    __syncthreads();
    if (rg == 0) {
        float sum = ((red[0][c] + red[1][c]) + (red[2][c] + red[3][c])) +
                    ((red[4][c] + red[5][c]) + (red[6][c] + red[7][c]));
        float cn = fmaxf((float)(e - s), 1.f);
        pr0b[g * HID + c] = f2b(sum / cn);
    }
}

// ================= fused edge + reaction MLPs via MFMA, 64 rows per block =================
__global__ __launch_bounds__(256) void edge_react_mfma(
    const u16* __restrict__ zb, const u16* __restrict__ nb,
    const int* __restrict__ pi, const int* __restrict__ pj,
    const u16* __restrict__ We1p, const float* __restrict__ be1,
    const u16* __restrict__ We2p, const float* __restrict__ be2,
    const float* __restrict__ We3, const float* __restrict__ be3,
    const u16* __restrict__ Wr1p, const float* __restrict__ br1,
    const float* __restrict__ Wr2, const float* __restrict__ br2,
    float* __restrict__ edgep, float* __restrict__ react) {
    __shared__ u16 inA[64 * 200];
    __shared__ u16 h1A[64 * 136];
    __shared__ u16 rhA[64 * 68];
    int t = threadIdx.x, w = t >> 6, l = t & 63, lr = l & 15, lg = l >> 4;
    int b = blockIdx.y, p0 = blockIdx.x * 64;
    for (int u = t; u < 1536; u += 256) {
        int r = u / 24, c8 = (u % 24) * 8;
        int p = min(p0 + r, NPAIR - 1);
        const u16* src;
        if (c8 < 64) src = zb + b * 64 + c8;
        else if (c8 < 128) src = nb + b * NODESF + pi[p] * 64 + (c8 - 64);
        else src = nb + b * NODESF + pj[p] * 64 + (c8 - 128);
        *(u16x8*)&inA[r * 200 + c8] = *(const u16x8*)src;
    }
    __syncthreads();
    f32x4 a1[4][2];
#pragma unroll
    for (int rt = 0; rt < 4; ++rt)
#pragma unroll
        for (int ct = 0; ct < 2; ++ct) a1[rt][ct] = (f32x4){0.f, 0.f, 0.f, 0.f};
#pragma unroll
    for (int ks = 0; ks < 6; ++ks) {
        bf16x8 af[4], bf_[2];
#pragma unroll
        for (int rt = 0; rt < 4; ++rt)
            af[rt] = *(const bf16x8*)&inA[(rt * 16 + lr) * 200 + ks * 32 + lg * 8];
#pragma unroll
        for (int ct = 0; ct < 2; ++ct) {
            int col = w * 32 + ct * 16 + lr;
            bf_[ct] = *(const bf16x8*)&We1p[(size_t)((ks * 4 + lg) * 128 + col) * 8];
        }
#pragma unroll
        for (int rt = 0; rt < 4; ++rt)
#pragma unroll
            for (int ct = 0; ct < 2; ++ct)
                a1[rt][ct] = __builtin_amdgcn_mfma_f32_16x16x32_bf16(af[rt], bf_[ct], a1[rt][ct], 0, 0, 0);
    }
    f32x4 r1[4];
#pragma unroll
    for (int rt = 0; rt < 4; ++rt) r1[rt] = (f32x4){0.f, 0.f, 0.f, 0.f};
#pragma unroll
    for (int ks = 0; ks < 4; ++ks) {
        bf16x8 af[4];
#pragma unroll
        for (int rt = 0; rt < 4; ++rt)
            af[rt] = *(const bf16x8*)&inA[(rt * 16 + lr) * 200 + 64 + ks * 32 + lg * 8];
        int col = w * 16 + lr;
        bf16x8 bf_ = *(const bf16x8*)&Wr1p[(size_t)((ks * 4 + lg) * 64 + col) * 8];
#pragma unroll
        for (int rt = 0; rt < 4; ++rt)
            r1[rt] = __builtin_amdgcn_mfma_f32_16x16x32_bf16(af[rt], bf_, r1[rt], 0, 0, 0);
    }
#pragma unroll
    for (int rt = 0; rt < 4; ++rt)
#pragma unroll
        for (int ct = 0; ct < 2; ++ct) {
            int col = w * 32 + ct * 16 + lr;
            float bia = be1[col];
#pragma unroll
            for (int i = 0; i < 4; ++i) {
                int row = rt * 16 + lg * 4 + i;
                h1A[row * 136 + col] = f2b(fmaxf(a1[rt][ct][i] + bia, 0.f));
            }
        }
#pragma unroll
    for (int rt = 0; rt < 4; ++rt) {
        int col = w * 16 + lr;
        float bia = br1[col];
#pragma unroll
        for (int i = 0; i < 4; ++i) {
            int row = rt * 16 + lg * 4 + i;
            rhA[row * 68 + col] = f2b(fmaxf(r1[rt][i] + bia, 0.f));
        }
    }
    __syncthreads();
    f32x4 a2[4];
#pragma unroll
    for (int rt = 0; rt < 4; ++rt) a2[rt] = (f32x4){0.f, 0.f, 0.f, 0.f};
#pragma unroll
    for (int ks = 0; ks < 4; ++ks) {
        bf16x8 af[4];
#pragma unroll
        for (int rt = 0; rt < 4; ++rt)
            af[rt] = *(const bf16x8*)&h1A[(rt * 16 + lr) * 136 + ks * 32 + lg * 8];
        int col = w * 16 + lr;
        bf16x8 bf_ = *(const bf16x8*)&We2p[(size_t)((ks * 4 + lg) * 64 + col) * 8];
#pragma unroll
        for (int rt = 0; rt < 4; ++rt)
            a2[rt] = __builtin_amdgcn_mfma_f32_16x16x32_bf16(af[rt], bf_, a2[rt], 0, 0, 0);
    }
    u16* h2A = inA;
#pragma unroll
    for (int rt = 0; rt < 4; ++rt) {
        int col = w * 16 + lr;
        float bia = be2[col];
#pragma unroll
        for (int i = 0; i < 4; ++i) {
            int row = rt * 16 + lg * 4 + i;
            h2A[row * 68 + col] = f2b(fmaxf(a2[rt][i] + bia, 0.f));
        }
    }
    __syncthreads();
    int r = t >> 2, sub = t & 3;
    int p = p0 + r;
    float acc3 = 0.f;
#pragma unroll
    for (int kk = 0; kk < 16; ++kk) {
        int c = sub * 16 + kk;
        acc3 = fmaf(b2f(h2A[r * 68 + c]), We3[c], acc3);
    }
    acc3 += __shfl_xor(acc3, 1);
    acc3 += __shfl_xor(acc3, 2);
    if (sub == 0 && p < NPAIR)
        edgep[b * NPAIR + p] = 1.f / (1.f + __expf(-(acc3 + be3[0])));
    float lg6[6] = {0.f, 0.f, 0.f, 0.f, 0.f, 0.f};
#pragma unroll
    for (int kk = 0; kk < 16; ++kk) {
        int c = sub * 16 + kk;
        float v = b2f(rhA[r * 68 + c]);
#pragma unroll
        for (int m = 0; m < 6; ++m) lg6[m] = fmaf(v, Wr2[c * 6 + m], lg6[m]);
    }
#pragma unroll
    for (int m = 0; m < 6; ++m) {
        lg6[m] += __shfl_xor(lg6[m], 1);
        lg6[m] += __shfl_xor(lg6[m], 2);
    }
    if (sub == 0 && p < NPAIR) {
        float mx = -3.4e38f;
#pragma unroll
        for (int m = 0; m < 6; ++m) { lg6[m] += br2[m]; mx = fmaxf(mx, lg6[m]); }
        float s = 0.f;
        float ex[6];
#pragma unroll
        for (int m = 0; m < 6; ++m) { ex[m] = __expf(lg6[m] - mx); s += ex[m]; }
        float rs = 1.f / s;
#pragma unroll
        for (int m = 0; m < 6; ++m) react[(size_t)(b * NPAIR + p) * 6 + m] = ex[m] * rs;
    }
}

// ================= launch =================
extern "C" void kernel_launch(void* const* d_in, const int* in_sizes, int n_in,
                              void* d_out, int out_size, void* d_ws, size_t ws_size,
                              hipStream_t stream) {
    const float* x     = (const float*)d_in[0];
    const int*   ei    = (const int*)d_in[1];
    const int*   batch = (const int*)d_in[2];
    const float* eps   = (const float*)d_in[3];
    const float* We    = (const float*)d_in[4];
    const float* be    = (const float*)d_in[5];
    const float* Wg    = (const float*)d_in[6];
    const float* ags   = (const float*)d_in[7];
    const float* agd   = (const float*)d_in[8];
    const float* bg    = (const float*)d_in[9];
    const float* Wa1   = (const float*)d_in[10];
    const float* ba1   = (const float*)d_in[11];
    const float* Wa2   = (const float*)d_in[12];
    const float* ba2   = (const float*)d_in[13];
    const float* Wmu   = (const float*)d_in[14];
    const float* bmu   = (const float*)d_in[15];
    const float* Wlv   = (const float*)d_in[16];
    const float* blv   = (const float*)d_in[17];
    const float* Wn1   = (const float*)d_in[18];
    const float* bn1   = (const float*)d_in[19];
    const float* Wn2   = (const float*)d_in[20];
    const float* bn2   = (const float*)d_in[21];
    const float* Wn3   = (const float*)d_in[22];
    const float* bn3   = (const float*)d_in[23];
    const float* We1   = (const float*)d_in[24];
    const float* be1   = (const float*)d_in[25];
    const float* We2   = (const float*)d_in[26];
    const float* be2   = (const float*)d_in[27];
    const float* We3   = (const float*)d_in[28];
    const float* be3   = (const float*)d_in[29];
    const float* Wr1   = (const float*)d_in[30];
    const float* br1   = (const float*)d_in[31];
    const float* Wr2   = (const float*)d_in[32];
    const float* br2   = (const float*)d_in[33];

    float* out = (float*)d_out;
    float* mu_o    = out;
    float* lv_o    = out + 4096;
    float* z_o     = out + 8192;
    float* pr_o    = out + 12288;
    float* nodep_o = out + 20480;
    float* edgep_o = out + 225280;
    float* react_o = out + 303680;

    float* F = (float*)d_ws;
    size_t o = 0;
    float* h  = F + o; o += (size_t)N_NODES * HID;
    float* es = F + o; o += (size_t)N_NODES * 4;
    float* ed = F + o; o += (size_t)N_NODES * 4;
    u16* U = (u16*)(F + o);
    size_t uo = 0;
    u16* hb     = U + uo; uo += (size_t)N_NODES * HID;
    u16* xb     = U + uo; uo += (size_t)N_NODES * NF;
    u16* xhb    = U + uo; uo += (size_t)N_NODES * HC;
    u16* zbf    = U + uo; uo += 4096;
    u16* nbf    = U + uo; uo += 64 * NODESF;
    u16* pr0b   = U + uo; uo += 64 * HID;
    u16* g2bb   = U + uo; uo += 64 * 512;
    u16* Wgp    = U + uo; uo += (size_t)3 * 16 * 512 * 8;
    u16* We1p   = U + uo; uo += 24 * 128 * 8;
    u16* We2p   = U + uo; uo += 16 * 64 * 8;
    u16* Wr1p   = U + uo; uo += 16 * 64 * 8;
    u16* Wa1p   = U + uo; uo += 16 * 256 * 8;
    u16* Wa2p   = U + uo; uo += 32 * 128 * 8;
    u16* Wmulvp = U + uo; uo += 16 * 128 * 8;
    u16* Wn1p   = U + uo; uo += 8 * 256 * 8;
    u16* Wn2p   = U + uo; uo += 32 * 512 * 8;
    u16* Wn3p   = U + uo; uo += (size_t)64 * 3200 * 8;
    u16* Wep    = U + uo; uo += 8 * 128 * 8;
    if (uo & 7) uo += 8 - (uo & 7);
    int* I = (int*)(U + uo);
    int* piA     = I;
    int* pjA     = piA + NPAIR;
    int* cursor  = pjA + NPAIR;                 // zeroed (N_NODES)
    int* csr_src = cursor + N_NODES;            // N_NODES * DEG_CAP

    // zero cursor every call — graph replays don't re-poison
    hipMemsetAsync(cursor, 0, (size_t)N_NODES * sizeof(int), stream);

    PackArgs pa;
    pa.src[0] = Wg;               pa.dst[0] = Wgp;
    pa.src[1] = Wg + 65536;       pa.dst[1] = Wgp + 65536;
    pa.src[2] = Wg + 131072;      pa.dst[2] = Wgp + 131072;
    pa.src[3] = We1;              pa.dst[3] = We1p;
    pa.src[4] = We2;              pa.dst[4] = We2p;
    pa.src[5] = Wr1;              pa.dst[5] = Wr1p;
    pa.src[6] = Wa1;              pa.dst[6] = Wa1p;
    pa.src[7] = Wa2;              pa.dst[7] = Wa2p;
    pa.src[8] = Wmu;              pa.dst[8] = Wmulvp;
    pa.src[9] = Wlv;              pa.dst[9] = Wmulvp;
    pa.src[10] = Wn1;             pa.dst[10] = Wn1p;
    pa.src[11] = Wn2;             pa.dst[11] = Wn2p;
    pa.src[12] = Wn3;             pa.dst[12] = Wn3p;
    pa.src[13] = We;              pa.dst[13] = Wep;
    pa.src[14] = x;               pa.dst[14] = xb;
    // pack + pairs + bucket CSR fill in one launch (memset precedes in stream order)
    pack_all_kernel<<<(PACK_GRID_TOTAL + 255) / 256, 256, 0, stream>>>(
        pa, piA, pjA, ei, cursor, csr_src);

    // h = relu(x @ We + be)
    gemm_mh_kernel<64, 128, 128, true, true, true>
        <<<dim3((N_NODES + 63) / 64, 1), 256, 0, stream>>>(xb, Wep, be, hb, h);

    // 3 GAT layers
    for (int l = 0; l < 3; ++l) {
        gemm_mh_kernel<128, 512, 64, false, false, false>
            <<<dim3((N_NODES + 63) / 64, 8), 256, 0, stream>>>(
                hb, Wgp + (size_t)l * 65536, nullptr, xhb, nullptr);
        esed_kernel<<<N_NODES / 4, 256, 0, stream>>>(xhb, ags + l * HC, agd + l * HC, es, ed);
        gat_agg_kernel<<<N_NODES / 4, 256, 0, stream>>>(xhb, es, ed, cursor, csr_src,
                                                        bg + l * HID, h, hb);
    }

    // pooling
    pool_kernel2<<<N_GRAPHS, 1024, 0, stream>>>(h, batch, pr0b);

    // fused VAE chain
    fused_vae_kernel<<<1, 256, 0, stream>>>(
        pr0b, eps, Wa1p, ba1, Wa2p, ba2, Wmulvp, bmu, blv,
        Wn1p, bn1, Wn2p, bn2, pr_o, mu_o, lv_o, z_o, zbf, g2bb);

    // nodes = sigmoid(g2 @ Wn3 + bn3) + raw bf16
    gemm64_kernel<512, 4, 2, false><<<200, 256, 0, stream>>>(
        g2bb, Wn3p, bn3, nullptr, nodep_o, nullptr, nbf, 3200);

    // fused edge + reaction MLPs
    edge_react_mfma<<<dim3(20, 64), 256, 0, stream>>>(
        zbf, nbf, piA, pjA, We1p, be1, We2p, be2, We3, be3,
        Wr1p, br1, Wr2, br2, edgep_o, react_o);
}